// Round 1
// baseline (340.880 us; speedup 1.0000x reference)
//
#include <hip/hip_runtime.h>
#include <hip/hip_bf16.h>

#define B_    16
#define M_    4096
#define K_    512
#define O_    512

#define BM 128
#define BN 128
#define BK 32
#define NT (K_ / BK)   // 16 K-tiles

typedef float f32x4 __attribute__((ext_vector_type(4)));
typedef short bf16x8 __attribute__((ext_vector_type(8)));
typedef unsigned short u16x8 __attribute__((ext_vector_type(8)));

// LDS chunk swizzle: tile is 128 rows x 4 k-quads of 16B chunks.
// chunk(row,kq) = row*4 + (kq ^ ((row>>1)&3))  -> <=2-way bank access on both
// the staging-write and fragment-read patterns (2-way is free on gfx950).
__device__ __forceinline__ int chunk_off(int row, int kq) {
    return (row * 4 + (kq ^ ((row >> 1) & 3))) * 8;   // ushort offset
}

// ---------------- kernel 1: s[b,i] = sum_f w[b,f]*A_w[i,f] + A_b[i] ----------------
__global__ void style_kernel(const float* __restrict__ w, const float* __restrict__ A_w,
                             const float* __restrict__ A_b, float* __restrict__ s) {
    int b = blockIdx.x;
    int i = blockIdx.y * 64 + threadIdx.x;
    __shared__ float wsh[512];
    for (int j = threadIdx.x; j < 512; j += 64) wsh[j] = w[b * 512 + j];
    __syncthreads();
    const float* arow = A_w + (size_t)i * 512;
    float acc = 0.f;
    #pragma unroll 4
    for (int f = 0; f < 512; f += 4) {
        float4 a = *(const float4*)(arow + f);
        acc += a.x * wsh[f] + a.y * wsh[f + 1] + a.z * wsh[f + 2] + a.w * wsh[f + 3];
    }
    s[b * 512 + i] = acc + A_b[i];
}

// ---------------- kernel 2: wd[b,o,i] = bf16(demodulated weight) ----------------
__global__ void demod_kernel(const float* __restrict__ weight, const float* __restrict__ s,
                             unsigned short* __restrict__ wd) {
    int gw = blockIdx.x * 4 + (threadIdx.x >> 6);
    int lane = threadIdx.x & 63;
    int b = gw >> 9;
    int o = gw & 511;
    const float* wrow = weight + (size_t)o * 512;
    const float* srow = s + b * 512;
    float vals[8];
    float ss = 0.f;
    #pragma unroll
    for (int j = 0; j < 8; j++) {
        int i = lane + j * 64;
        float v = wrow[i] * srow[i];
        vals[j] = v;
        ss += v * v;
    }
    #pragma unroll
    for (int off = 32; off; off >>= 1) ss += __shfl_xor(ss, off);
    float nrm = rsqrtf(1e-8f + ss);
    unsigned short* drow = wd + ((size_t)b * 512 + o) * 512;
    #pragma unroll
    for (int j = 0; j < 8; j++) {
        int i = lane + j * 64;
        unsigned int u = __builtin_bit_cast(unsigned int, vals[j] * nrm);
        u += 0x7fffu + ((u >> 16) & 1u);
        drow[i] = (unsigned short)(u >> 16);
    }
}

// ---------------- kernel 3: out[b,n,o] = relu( x[b]·wd[b]^T + bias ) ----------------
//
// v2: triple-buffered LDS, prefetch distance 2, raw s_barrier + counted
// s_waitcnt vmcnt(6) (the 6 newest VMEM ops — tile k+2's 2 B-DMAs + 4 A-loads —
// stay in flight across the barrier). No vmcnt(0) drain in the main loop.
// The "memory" clobber on each fence pins every iteration's memory ops between
// its two barriers, so "all but the newest 6 complete" == "tile k+1 ready".

#define ISSUE_B(tile, buf)                                                              \
    _Pragma("unroll")                                                                   \
    for (int j = 0; j < 2; j++) {                                                       \
        __builtin_amdgcn_global_load_lds(                                               \
            (const __attribute__((address_space(1))) unsigned int*)(                    \
                wdb + (size_t)(n0 + brow[j]) * K_ + (tile) * BK + bkq[j] * 8),          \
            (__attribute__((address_space(3))) unsigned int*)(&sB[buf][bchunk[j] * 8]), \
            16, 0, 0);                                                                  \
    }

#define LOAD_A(tile, regs)                                                              \
    _Pragma("unroll")                                                                   \
    for (int j = 0; j < 4; j++) regs[j] = *(const f32x4*)(abase + (tile) * BK + j * 4);

#define CVT_A(regs, buf)                                                                \
    _Pragma("unroll")                                                                   \
    for (int j = 0; j < 2; j++) {                                                       \
        union { __hip_bfloat162 h[4]; u16x8 v; } cv;                                    \
        cv.h[0] = __float22bfloat162_rn(float2{regs[2*j][0], regs[2*j][1]});            \
        cv.h[1] = __float22bfloat162_rn(float2{regs[2*j][2], regs[2*j][3]});            \
        cv.h[2] = __float22bfloat162_rn(float2{regs[2*j+1][0], regs[2*j+1][1]});        \
        cv.h[3] = __float22bfloat162_rn(float2{regs[2*j+1][2], regs[2*j+1][3]});        \
        *(u16x8*)(&sA[buf][chunk_off(ar, akq0 + j)]) = cv.v;                            \
    }

#define COMPUTE(buf)                                                                    \
    {                                                                                   \
        bf16x8 af[4], bfr[4];                                                           \
        _Pragma("unroll")                                                               \
        for (int mi = 0; mi < 4; mi++) af[mi] = *(const bf16x8*)(&sA[buf][offA[mi]]);   \
        _Pragma("unroll")                                                               \
        for (int ni = 0; ni < 4; ni++) bfr[ni] = *(const bf16x8*)(&sB[buf][offB[ni]]);  \
        _Pragma("unroll")                                                               \
        for (int mi = 0; mi < 4; mi++)                                                  \
            _Pragma("unroll")                                                           \
            for (int ni = 0; ni < 4; ni++)                                              \
                acc[mi][ni] = __builtin_amdgcn_mfma_f32_16x16x32_bf16(                  \
                    af[mi], bfr[ni], acc[mi][ni], 0, 0, 0);                             \
    }

#define FENCE6() do {                                                                   \
    asm volatile("s_waitcnt vmcnt(6) lgkmcnt(0)" ::: "memory");                         \
    __builtin_amdgcn_s_barrier();                                                       \
} while (0)

#define FENCE0() do {                                                                   \
    asm volatile("s_waitcnt vmcnt(0) lgkmcnt(0)" ::: "memory");                         \
    __builtin_amdgcn_s_barrier();                                                       \
} while (0)

__global__ __launch_bounds__(256, 3) void gemm_kernel(const float* __restrict__ x,
                                                      const unsigned short* __restrict__ wd,
                                                      const float* __restrict__ bias,
                                                      float* __restrict__ out) {
    // triple-buffered, chunk-swizzled tiles (8 KB each buffer per operand, 48 KB total)
    __shared__ unsigned short sA[3][BM * BK];
    __shared__ unsigned short sB[3][BN * BK];

    // XCD swizzle: consecutive blocks round-robin XCDs; give each XCD a
    // contiguous mb range (2 b-values -> wd slice 1MB L2-resident) and put the
    // 4 n-blocks sharing an x-tile back-to-back on the same XCD.
    int g = blockIdx.x;
    int xcd = g & 7;
    int grp = g >> 3;                  // [0,256)
    int nblk = grp & 3;
    int mb = xcd * 64 + (grp >> 2);    // [0,512)
    const int b  = mb >> 5;
    const int m0 = (mb & 31) * BM;
    const int n0 = nblk * BN;

    const float* xb = x + (size_t)b * M_ * K_;
    const unsigned short* wdb = wd + (size_t)b * O_ * K_;

    const int t = threadIdx.x;
    const int w = t >> 6;
    const int l = t & 63;
    const int wave_row = (w >> 1) * 64;
    const int wave_col = (w & 1) * 64;
    const int lrow  = l & 15;
    const int kq_l  = l >> 4;

    // iteration-invariant fragment offsets (swizzled)
    int offA[4], offB[4];
    #pragma unroll
    for (int mi = 0; mi < 4; mi++)
        offA[mi] = chunk_off(wave_row + mi * 16 + lrow, kq_l);
    #pragma unroll
    for (int ni = 0; ni < 4; ni++)
        offB[ni] = chunk_off(wave_col + ni * 16 + lrow, kq_l);

    // A staging geometry: thread t covers row r = t>>1, 16 floats starting at (t&1)*16
    const int ar = t >> 1;
    const int akq0 = (t & 1) * 2;
    const float* abase = xb + (size_t)(m0 + ar) * K_ + akq0 * 8;

    // B staging geometry: instr j writes chunks [w*128 + j*64 + lane]
    int bchunk[2], brow[2], bkq[2];
    #pragma unroll
    for (int j = 0; j < 2; j++) {
        int c = w * 128 + j * 64 + l;
        brow[j] = c >> 2;
        bkq[j] = (c & 3) ^ ((brow[j] >> 1) & 3);
        bchunk[j] = c;
    }

    f32x4 acc[4][4] = {};
    f32x4 areg0[4], areg1[4];

    // ---- prologue: stage tiles 0 and 1 (B via DMA, A into regs), convert A0 ----
    ISSUE_B(0, 0);
    LOAD_A(0, areg0);
    asm volatile("" ::: "memory");   // pin tile-0 issues before tile-1 issues
    ISSUE_B(1, 1);
    LOAD_A(1, areg1);
    CVT_A(areg0, 0);                 // compiler waits A0; vmcnt(6) below covers B0
    FENCE6();                        // leaves {B1 x2, A1 x4} in flight

    // ---- main loop: one raw barrier per K-tile, distance-2 prefetch ----
    #pragma unroll
    for (int k = 0; k < NT; k++) {
        if (k + 2 < NT) {
            ISSUE_B(k + 2, (k + 2) % 3);
            if ((k & 1) == 0) { LOAD_A(k + 2, areg0); } else { LOAD_A(k + 2, areg1); }
        }

        COMPUTE(k % 3);

        if (k + 1 < NT) {
            // convert+store A[k+1] (loaded one iteration ago; MFMA phase above
            // gave its loads an extra ~full phase to land)
            if ((k & 1) == 0) { CVT_A(areg1, (k + 1) % 3); } else { CVT_A(areg0, (k + 1) % 3); }
            if (k + 2 < NT) { FENCE6(); } else { FENCE0(); }
        }
    }

    // epilogue: C/D layout col=lane&15, row=(lane>>4)*4+reg  [m89-verified]
    const int col_l = l & 15;
    const int row_q = (l >> 4) * 4;
    #pragma unroll
    for (int ni = 0; ni < 4; ni++) {
        int o = n0 + wave_col + ni * 16 + col_l;
        float bv = bias[o];
        #pragma unroll
        for (int mi = 0; mi < 4; mi++) {
            int mrow = m0 + wave_row + mi * 16 + row_q;
            #pragma unroll
            for (int r = 0; r < 4; r++) {
                float v = acc[mi][ni][r] + bv;
                out[((size_t)b * M_ + mrow + r) * O_ + o] = v > 0.f ? v : 0.f;
            }
        }
    }
}

extern "C" void kernel_launch(void* const* d_in, const int* in_sizes, int n_in,
                              void* d_out, int out_size, void* d_ws, size_t ws_size,
                              hipStream_t stream) {
    const float* x      = (const float*)d_in[0];
    const float* w      = (const float*)d_in[1];
    const float* weight = (const float*)d_in[2];
    const float* bias   = (const float*)d_in[3];
    const float* A_w    = (const float*)d_in[4];
    const float* A_b    = (const float*)d_in[5];
    float* out = (float*)d_out;

    unsigned short* wd = (unsigned short*)d_ws;                              // 8.4 MB
    float* s = (float*)((char*)d_ws + (size_t)B_ * O_ * K_ * sizeof(unsigned short));

    style_kernel<<<dim3(B_, 8), 64, 0, stream>>>(w, A_w, A_b, s);
    demod_kernel<<<(B_ * O_) / 4, 256, 0, stream>>>(weight, s, wd);
    gemm_kernel<<<2048, 256, 0, stream>>>(x, wd, bias, out);
}

// Round 2
// 273.917 us; speedup vs baseline: 1.2445x; 1.2445x over previous
//
#include <hip/hip_runtime.h>
#include <hip/hip_bf16.h>

#define B_    16
#define M_    4096
#define K_    512
#define O_    512

#define BM 64
#define NT 16   // K-tiles of 32

typedef float f32x4 __attribute__((ext_vector_type(4)));
typedef short bf16x8 __attribute__((ext_vector_type(8)));
typedef unsigned short u16x8 __attribute__((ext_vector_type(8)));

// ---------------- kernel 1: s[b,i] = sum_f w[b,f]*A_w[i,f] + A_b[i] ----------------
// 32 blocks x 256 threads; block covers 16 i-values for ALL 16 b.
// A_w read exactly once across the grid; w broadcast from LDS (padded rows,
// stride 516 floats -> 4-bank skew per row, broadcast reads are free).
__global__ void style_kernel(const float* __restrict__ w, const float* __restrict__ A_w,
                             const float* __restrict__ A_b, float* __restrict__ s) {
    __shared__ float wsh[16][516];
    __shared__ float ash[16][516];
    int t = threadIdx.x;
    for (int idx = t; idx < 2048; idx += 256) {
        int row = idx >> 7, q = (idx & 127) * 4;
        *(float4*)&wsh[row][q] = *(const float4*)&w[row * 512 + q];
    }
    int i0 = blockIdx.x * 16;
    for (int idx = t; idx < 2048; idx += 256) {
        int row = idx >> 7, q = (idx & 127) * 4;
        *(float4*)&ash[row][q] = *(const float4*)&A_w[(size_t)(i0 + row) * 512 + q];
    }
    __syncthreads();
    int b = t >> 4, il = t & 15;
    float acc = 0.f;
    #pragma unroll 8
    for (int f = 0; f < 512; f += 4) {
        float4 wa = *(const float4*)&wsh[b][f];
        float4 aa = *(const float4*)&ash[il][f];
        acc += wa.x * aa.x + wa.y * aa.y + wa.z * aa.z + wa.w * aa.w;
    }
    s[b * 512 + i0 + il] = acc + A_b[i0 + il];
}

// ---------------- kernel 2: demodulate -> bf16, FRAGMENT-TILED layout ----------------
// wd2 element (b, o, k) with k = ks*32 + kq*8 + j lives at
//   ((((b*16 + ks)*32 + (o>>4))*4 + kq)*16 + (o&15))*8 + j
// so a GEMM B-fragment (b, ks, colgroup cg) is 1 KB contiguous with lane l at
// byte offset l*16 (cl = l&15, kq = l>>4) -> one coalesced global_load_dwordx4.
__global__ void demod_kernel(const float* __restrict__ weight, const float* __restrict__ s,
                             unsigned short* __restrict__ wd2) {
    int gw = blockIdx.x * 4 + (threadIdx.x >> 6);
    int lane = threadIdx.x & 63;
    int b = gw >> 9;
    int o = gw & 511;
    const float* wrow = weight + (size_t)o * 512;
    const float* srow = s + b * 512;
    int k0 = lane * 8;                       // lane holds k = k0..k0+7 (contiguous)
    f32x4 w0 = *(const f32x4*)(wrow + k0);
    f32x4 w1 = *(const f32x4*)(wrow + k0 + 4);
    f32x4 s0 = *(const f32x4*)(srow + k0);
    f32x4 s1 = *(const f32x4*)(srow + k0 + 4);
    float vals[8];
    float ss = 0.f;
    #pragma unroll
    for (int j = 0; j < 4; j++) { float v = w0[j] * s0[j]; vals[j] = v; ss += v * v; }
    #pragma unroll
    for (int j = 0; j < 4; j++) { float v = w1[j] * s1[j]; vals[4 + j] = v; ss += v * v; }
    #pragma unroll
    for (int off = 32; off; off >>= 1) ss += __shfl_xor(ss, off);
    float nrm = rsqrtf(1e-8f + ss);
    int ks = lane >> 2, kq = lane & 3;
    size_t base = (((((size_t)b * 16 + ks) * 32 + (o >> 4)) * 4 + kq) * 16 + (o & 15)) * 8;
    u16x8 pack;
    #pragma unroll
    for (int j = 0; j < 8; j++) {
        unsigned int u = __builtin_bit_cast(unsigned int, vals[j] * nrm);
        u += 0x7fffu + ((u >> 16) & 1u);
        pack[j] = (unsigned short)(u >> 16);
    }
    *(u16x8*)(wd2 + base) = pack;
}

// ---------------- kernel 3: out[b,n,o] = relu( x[b]·wd[b]^T + bias ) ----------------
// BM=64 x BN=512 (full output width): x read EXACTLY ONCE across the grid.
// Whole 64x512 x-panel converted to bf16 and resident in LDS (64 KB, XOR-swizzled
// chunks: phys(row,c) = row*64 + (c&~7) + ((c^row)&7) -> uniform 8 chunk-banks on
// both the b128 write and read patterns). Main loop: NO barriers, NO LDS writes —
// B fragments stream straight from L2 (wd2 tiled layout), waves self-paced.
__global__ __launch_bounds__(256, 2) void gemm_kernel(const float* __restrict__ x,
                                                      const unsigned short* __restrict__ wd2,
                                                      const float* __restrict__ bias,
                                                      float* __restrict__ out) {
    __shared__ unsigned short sA[BM * 64 * 8];   // 64 rows x 64 chunks x 16 B = 64 KB

    // XCD swizzle: XCD gets 2 consecutive b values (2 x 512 KB wd2 panels L2-resident),
    // consecutive same-XCD blocks are consecutive m-blocks of one b.
    int g = blockIdx.x;
    int xcd = g & 7;
    int r = g >> 3;                  // [0,128)
    const int b  = xcd * 2 + (r >> 6);
    const int m0 = (r & 63) * BM;

    const int t = threadIdx.x;
    const int w = t >> 6;
    const int l = t & 63;

    // ---- prologue: stage x panel (64x512 fp32 -> bf16 LDS), one barrier ----
    const float* xb = x + ((size_t)b * M_ + m0) * K_;
    #pragma unroll
    for (int rr = 0; rr < 16; rr++) {
        int row = rr * 4 + w;                       // wave-uniform row
        const float* src = xb + (size_t)row * K_ + l * 8;
        f32x4 u = *(const f32x4*)src;
        f32x4 v = *(const f32x4*)(src + 4);
        union { __hip_bfloat162 h[4]; u16x8 vv; } cv;
        cv.h[0] = __float22bfloat162_rn(float2{u[0], u[1]});
        cv.h[1] = __float22bfloat162_rn(float2{u[2], u[3]});
        cv.h[2] = __float22bfloat162_rn(float2{v[0], v[1]});
        cv.h[3] = __float22bfloat162_rn(float2{v[2], v[3]});
        int chunk = row * 64 + (l & ~7) + ((l ^ row) & 7);
        *(u16x8*)(&sA[chunk * 8]) = cv.vv;
    }
    __syncthreads();   // the ONLY barrier in this kernel

    // B fragment base: frag(ks,ni) = wb + (ks*32 + ni)*512 elems, lane offset l*8
    const unsigned short* wb = wd2 + (size_t)b * 262144 + (size_t)(w * 8) * 512 + (size_t)l * 8;

    const int rowl = l & 15;
    const int kqv  = l >> 4;

    f32x4 acc[4][8] = {};
    bf16x8 bfr[2][8];

    #pragma unroll
    for (int ni = 0; ni < 8; ni++)
        bfr[0][ni] = *(const bf16x8*)(wb + (size_t)ni * 512);

    #pragma unroll
    for (int ks = 0; ks < NT; ks++) {
        // distance-1 prefetch of next B fragments (independent regs, no WAR)
        if (ks + 1 < NT) {
            #pragma unroll
            for (int ni = 0; ni < 8; ni++)
                bfr[(ks + 1) & 1][ni] = *(const bf16x8*)(wb + ((size_t)(ks + 1) * 32 + ni) * 512);
        }
        // A fragments from resident LDS panel (swizzled; imm-offset friendly)
        bf16x8 af[4];
        #pragma unroll
        for (int mi = 0; mi < 4; mi++) {
            int row = mi * 16 + rowl;
            int c = ks * 4 + kqv;
            int chunk = row * 64 + (c & ~7) + ((c ^ row) & 7);
            af[mi] = *(const bf16x8*)(&sA[chunk * 8]);
        }
        __builtin_amdgcn_s_setprio(1);
        #pragma unroll
        for (int mi = 0; mi < 4; mi++)
            #pragma unroll
            for (int ni = 0; ni < 8; ni++)
                acc[mi][ni] = __builtin_amdgcn_mfma_f32_16x16x32_bf16(af[mi], bfr[ks & 1][ni], acc[mi][ni], 0, 0, 0);
        __builtin_amdgcn_s_setprio(0);
    }

    // epilogue: C/D layout col=lane&15, row=(lane>>4)*4+reg  [m89-verified]
    const int col_l = l & 15;
    const int row_q = (l >> 4) * 4;
    #pragma unroll
    for (int ni = 0; ni < 8; ni++) {
        int o = w * 128 + ni * 16 + col_l;
        float bv = bias[o];
        #pragma unroll
        for (int mi = 0; mi < 4; mi++) {
            int mrow = m0 + mi * 16 + row_q;
            #pragma unroll
            for (int rr2 = 0; rr2 < 4; rr2++) {
                float v = acc[mi][ni][rr2] + bv;
                out[((size_t)b * M_ + mrow + rr2) * O_ + o] = v > 0.f ? v : 0.f;
            }
        }
    }
}

extern "C" void kernel_launch(void* const* d_in, const int* in_sizes, int n_in,
                              void* d_out, int out_size, void* d_ws, size_t ws_size,
                              hipStream_t stream) {
    const float* x      = (const float*)d_in[0];
    const float* w      = (const float*)d_in[1];
    const float* weight = (const float*)d_in[2];
    const float* bias   = (const float*)d_in[3];
    const float* A_w    = (const float*)d_in[4];
    const float* A_b    = (const float*)d_in[5];
    float* out = (float*)d_out;

    unsigned short* wd2 = (unsigned short*)d_ws;                             // 8.4 MB tiled
    float* s = (float*)((char*)d_ws + (size_t)B_ * O_ * K_ * sizeof(unsigned short));

    style_kernel<<<32, 256, 0, stream>>>(w, A_w, A_b, s);
    demod_kernel<<<(B_ * O_) / 4, 256, 0, stream>>>(weight, s, wd2);
    gemm_kernel<<<1024, 256, 0, stream>>>(x, wd2, bias, out);
}